// Round 3
// baseline (2345.714 us; speedup 1.0000x reference)
//
#include <hip/hip_runtime.h>
#include <math.h>

#define NN 100000
#define DD 128
#define CC 64
#define TT 8
#define NS 50000

typedef __attribute__((ext_vector_type(4))) float f32x4;
typedef __attribute__((ext_vector_type(8))) short bf16x8;

__device__ __forceinline__ short f2bf(float f) {
    union { float f; unsigned u; } v; v.f = f;
    unsigned r = v.u + 0x7fffu + ((v.u >> 16) & 1u);
    return (short)(r >> 16);
}
// tanh-form GELU via hardware exp: max |diff| vs exact erf-GELU ~3e-3
__device__ __forceinline__ float gelu(float x) {
    float t = x + 0.044715f * x * x * x;
    return x / (1.0f + __expf(-1.5957691216f * t));
}

// ---------------- weight -> MFMA-fragment prearrange (bf16) ----------------
__global__ void prep_weights(const float* __restrict__ W, short* __restrict__ dst,
                             int KSTEPS, int total, int N) {
    int s = blockIdx.x * 256 + threadIdx.x;
    if (s >= total) return;
    int lane = s & 63;
    int ks = (s >> 6) % KSTEPS;
    int n = s / (64 * KSTEPS);
    int kb = ks * 32 + (lane >> 4) * 8;
    int col = n * 16 + (lane & 15);
    bf16x8 o;
    #pragma unroll
    for (int j = 0; j < 8; ++j) o[j] = f2bf(W[(size_t)(kb + j) * N + col]);
    *(bf16x8*)(dst + (size_t)s * 8) = o;
}

// ---------------- per-(node,g) contribution counts ----------------
__global__ void flag_kernel(const int* __restrict__ idx, int* __restrict__ pernode, int G) {
    int i = blockIdx.x * 256 + threadIdx.x;
    if (i >= G * NS) return;
    int g = i / NS;
    atomicAdd(&pernode[idx[i] * 8 + g], 1);
}

// ---------------- zero active table rows + build per-g lists ----------------
__global__ void zero_compact_kernel(const int* __restrict__ pernode,
                                    int* __restrict__ lists, int* __restrict__ cnts,
                                    float* __restrict__ tables, int G) {
    int t = blockIdx.x * 256 + threadIdx.x;   // 4 lanes per node
    int node = t >> 2, q = t & 3;
    if (node >= NN) return;                    // quad-uniform exit
    int2 c = *(const int2*)(pernode + node * 8 + q * 2);
    unsigned m = ((c.x > 0) ? 1u : 0u) | ((c.y > 0) ? 2u : 0u);
    m <<= (q * 2);
    m |= __shfl_xor(m, 1);
    m |= __shfl_xor(m, 2);
    if (!m) return;
    while (m) {
        int g = __ffs(m) - 1; m &= m - 1;
        if (g >= G) break;
        if (q == 0) { int p = atomicAdd(&cnts[g], 1); lists[(size_t)g * NS + p] = node; }
        float4 z = {0.f, 0.f, 0.f, 0.f};
        float4* dst = (float4*)(tables + (size_t)g * (NN * DD) + (size_t)node * DD + q * 32);
        #pragma unroll
        for (int j = 0; j < 8; ++j) dst[j] = z;
    }
}

// ---------------- scatter: plain store when unique, atomics otherwise -------
__global__ void scatter_kernel(const float* __restrict__ x, const int* __restrict__ idx,
                               const int* __restrict__ pernode,
                               float* __restrict__ tables, int G) {
    int tid = blockIdx.x * 256 + threadIdx.x;  // G*NS*32
    int i = tid >> 5;
    if (i >= G * NS) return;
    int g = i / NS;
    int d4 = (tid & 31) * 4;
    int node = idx[i];
    float4 v = *(const float4*)(x + (size_t)i * DD + d4);
    float* dst = tables + (size_t)g * (NN * DD) + (size_t)node * DD + d4;
    if (pernode[node * 8 + g] == 1) {
        *(float4*)dst = v;
    } else {
        atomicAdd(dst + 0, v.x); atomicAdd(dst + 1, v.y);
        atomicAdd(dst + 2, v.z); atomicAdd(dst + 3, v.w);
    }
}

// ---------------- fused mlp_d over all groups: LN -> G1+GELU -> G2 ----------
// 512 threads = 8 waves, 16 rows/wave, strip=128 rows. LDS 160KB -> 1 block/CU.
__global__ __launch_bounds__(512, 2) void mlp_d_kernel(
    const float* __restrict__ tables, const float* __restrict__ bd,
    const float* __restrict__ lng, const float* __restrict__ lnb,
    const short* __restrict__ pW1, const short* __restrict__ pW2,
    const float* __restrict__ bd1, const float* __restrict__ bd2,
    const int* __restrict__ lists, const int* __restrict__ cnts,
    int* __restrict__ pernode, float* __restrict__ h, int G) {
    __shared__ short sW1[4096 * 8];
    __shared__ short sW2[2048 * 8];
    __shared__ short sAH[8][4096];  // per-wave: A [16][128] in [0,2048), H [16][256] in [0,4096)

    const int tid = threadIdx.x;
    for (int s = tid; s < 4096; s += 512)
        *(bf16x8*)(sW1 + s * 8) = *(const bf16x8*)(pW1 + (size_t)s * 8);
    for (int s = tid; s < 2048; s += 512)
        *(bf16x8*)(sW2 + s * 8) = *(const bf16x8*)(pW2 + (size_t)s * 8);
    __syncthreads();

    const int wave = tid >> 6, lane = tid & 63;
    short* myb = sAH[wave];
    const int arow = lane & 15;
    const int kgrp = lane >> 4;
    const int swa = (arow & 7) << 4;
    const int MAXS = (NS + 127) / 128;   // 391

    for (int w = blockIdx.x; w < G * MAXS; w += gridDim.x) {
        const int g = w % G;
        const int strip = w / G;
        const int nrows = cnts[g];
        if (strip * 128 >= nrows) continue;
        const float* table = tables + (size_t)g * (NN * DD);
        const int* list = lists + (size_t)g * NS;
        float* h_t = h + (size_t)g * (NN * CC);
        const int row0 = strip * 128 + wave * 16;

        // ---- LN (4 lanes/row, 32 cols/lane) -> swizzled bf16 A
        {
            const int r = lane >> 2;
            const int c0 = (lane & 3) * 32;
            const int gi = row0 + r;
            const int node = list[gi < nrows ? gi : (nrows - 1)];
            const float* tp = table + (size_t)node * DD + c0;
            const float* bp = bd + (size_t)node * DD + c0;
            float v[32];
            float s1 = 0.f;
            #pragma unroll
            for (int j = 0; j < 8; ++j) {
                float4 a = ((const float4*)tp)[j];
                float4 c = ((const float4*)bp)[j];
                v[j * 4 + 0] = a.x + c.x; v[j * 4 + 1] = a.y + c.y;
                v[j * 4 + 2] = a.z + c.z; v[j * 4 + 3] = a.w + c.w;
                s1 += v[j * 4 + 0] + v[j * 4 + 1] + v[j * 4 + 2] + v[j * 4 + 3];
            }
            s1 += __shfl_xor(s1, 1); s1 += __shfl_xor(s1, 2);
            float mu = s1 * 0.0078125f;
            float s2 = 0.f;
            #pragma unroll
            for (int j = 0; j < 32; ++j) { float d = v[j] - mu; s2 += d * d; }
            s2 += __shfl_xor(s2, 1); s2 += __shfl_xor(s2, 2);
            float rs = rsqrtf(s2 * 0.0078125f + 1e-5f);
            short ov[32];
            #pragma unroll
            for (int j = 0; j < 8; ++j) {
                float4 gv = ((const float4*)(lng + c0))[j];
                float4 bv = ((const float4*)(lnb + c0))[j];
                ov[j * 4 + 0] = f2bf((v[j * 4 + 0] - mu) * rs * gv.x + bv.x);
                ov[j * 4 + 1] = f2bf((v[j * 4 + 1] - mu) * rs * gv.y + bv.y);
                ov[j * 4 + 2] = f2bf((v[j * 4 + 2] - mu) * rs * gv.z + bv.z);
                ov[j * 4 + 3] = f2bf((v[j * 4 + 3] - mu) * rs * gv.w + bv.w);
            }
            const int swr = (r & 7) << 4;
            #pragma unroll
            for (int q = 0; q < 4; ++q) {
                int boff = (c0 * 2 + q * 16) ^ swr;
                *(bf16x8*)(myb + r * 128 + (boff >> 1)) = *(bf16x8*)(ov + q * 8);
            }
        }
        // ---- GEMM1 (16x256, K=128)
        f32x4 acc[16];
        #pragma unroll
        for (int n = 0; n < 16; ++n) acc[n] = (f32x4){0.f, 0.f, 0.f, 0.f};
        #pragma unroll
        for (int ks = 0; ks < 4; ++ks) {
            int boff = (ks * 64 + kgrp * 16) ^ swa;
            bf16x8 af = *(const bf16x8*)(myb + arow * 128 + (boff >> 1));
            #pragma unroll
            for (int n = 0; n < 16; ++n) {
                bf16x8 bf = *(const bf16x8*)(sW1 + (size_t)(((n << 2) | ks) * 64 + lane) * 8);
                acc[n] = __builtin_amdgcn_mfma_f32_16x16x32_bf16(af, bf, acc[n], 0, 0, 0);
            }
        }
        // ---- bias + GELU -> swizzled bf16 H
        #pragma unroll
        for (int n = 0; n < 16; ++n) {
            float bias = bd1[n * 16 + arow];
            #pragma unroll
            for (int rr = 0; rr < 4; ++rr) {
                float vv = gelu(acc[n][rr] + bias);
                int hr = kgrp * 4 + rr;
                int boff = ((n * 16 + arow) * 2) ^ ((hr & 7) << 4);
                myb[hr * 256 + (boff >> 1)] = f2bf(vv);
            }
        }
        // ---- GEMM2 (16x64, K=256)
        f32x4 acc2[4];
        #pragma unroll
        for (int n = 0; n < 4; ++n) acc2[n] = (f32x4){0.f, 0.f, 0.f, 0.f};
        #pragma unroll
        for (int ks = 0; ks < 8; ++ks) {
            int boff = (ks * 64 + kgrp * 16) ^ swa;
            bf16x8 af = *(const bf16x8*)(myb + arow * 256 + (boff >> 1));
            #pragma unroll
            for (int n = 0; n < 4; ++n) {
                bf16x8 bf = *(const bf16x8*)(sW2 + (size_t)(((n << 3) | ks) * 64 + lane) * 8);
                acc2[n] = __builtin_amdgcn_mfma_f32_16x16x32_bf16(af, bf, acc2[n], 0, 0, 0);
            }
        }
        // ---- epilogue: h[node] + clear pernode for next replay/group
        #pragma unroll
        for (int rr = 0; rr < 4; ++rr) {
            int gi2 = row0 + kgrp * 4 + rr;
            if (gi2 < nrows) {
                int node2 = list[gi2];
                if (arow == 0) pernode[node2 * 8 + g] = 0;
                #pragma unroll
                for (int n = 0; n < 4; ++n)
                    h_t[(size_t)node2 * CC + n * 16 + arow] = acc2[n][rr] + bd2[n * 16 + arow];
            }
        }
    }
}

// ---------------- fused mlp_u over all groups -------------------------------
__global__ __launch_bounds__(512, 4) void mlp_u_kernel(
    const float* __restrict__ h, const int* __restrict__ idx,
    const float* __restrict__ lng, const float* __restrict__ lnb,
    const short* __restrict__ pW3, const short* __restrict__ pW4,
    const float* __restrict__ bu1, const float* __restrict__ bu2,
    float* __restrict__ out, int G) {
    __shared__ short sW3[1024 * 8];
    __shared__ short sW4[2048 * 8];
    __shared__ short sAU[8][2048];

    const int tid = threadIdx.x;
    for (int s = tid; s < 1024; s += 512)
        *(bf16x8*)(sW3 + s * 8) = *(const bf16x8*)(pW3 + (size_t)s * 8);
    for (int s = tid; s < 2048; s += 512)
        *(bf16x8*)(sW4 + s * 8) = *(const bf16x8*)(pW4 + (size_t)s * 8);
    __syncthreads();

    const int wave = tid >> 6, lane = tid & 63;
    short* myb = sAU[wave];
    const int arow = lane & 15;
    const int kgrp = lane >> 4;
    const int swa = (arow & 7) << 4;
    const int MAXS = (NS + 127) / 128;   // 391

    for (int w = blockIdx.x; w < G * MAXS; w += gridDim.x) {
        const int g = w % G;
        const int strip = w / G;
        const int* idx_t = idx + (size_t)g * NS;
        const float* h_t = h + (size_t)g * (NN * CC);
        float* out_t = out + (size_t)g * NS * DD;
        const int row0 = strip * 128 + wave * 16;

        // ---- gather + LN (4 lanes/row, 16 cols/lane)
        {
            const int r = lane >> 2;
            const int c0 = (lane & 3) * 16;
            const int gi = row0 + r;
            const int srow = gi < NS ? gi : (NS - 1);
            const int node = idx_t[srow];
            const float* hp = h_t + (size_t)node * CC + c0;
            float v[16];
            float s1 = 0.f;
            #pragma unroll
            for (int j = 0; j < 4; ++j) {
                float4 a = ((const float4*)hp)[j];
                v[j * 4 + 0] = a.x; v[j * 4 + 1] = a.y; v[j * 4 + 2] = a.z; v[j * 4 + 3] = a.w;
                s1 += a.x + a.y + a.z + a.w;
            }
            s1 += __shfl_xor(s1, 1); s1 += __shfl_xor(s1, 2);
            float mu = s1 * 0.015625f;
            float s2 = 0.f;
            #pragma unroll
            for (int j = 0; j < 16; ++j) { float d = v[j] - mu; s2 += d * d; }
            s2 += __shfl_xor(s2, 1); s2 += __shfl_xor(s2, 2);
            float rs = rsqrtf(s2 * 0.015625f + 1e-5f);
            short ov[16];
            #pragma unroll
            for (int j = 0; j < 4; ++j) {
                float4 gv = ((const float4*)(lng + c0))[j];
                float4 bv = ((const float4*)(lnb + c0))[j];
                ov[j * 4 + 0] = f2bf((v[j * 4 + 0] - mu) * rs * gv.x + bv.x);
                ov[j * 4 + 1] = f2bf((v[j * 4 + 1] - mu) * rs * gv.y + bv.y);
                ov[j * 4 + 2] = f2bf((v[j * 4 + 2] - mu) * rs * gv.z + bv.z);
                ov[j * 4 + 3] = f2bf((v[j * 4 + 3] - mu) * rs * gv.w + bv.w);
            }
            const int swr = (r & 7) << 4;
            #pragma unroll
            for (int q = 0; q < 2; ++q) {
                int boff = (c0 * 2 + q * 16) ^ swr;
                *(bf16x8*)(myb + r * 64 + (boff >> 1)) = *(bf16x8*)(ov + q * 8);
            }
        }
        // ---- GEMM3 (16x128, K=64)
        f32x4 a3[8];
        #pragma unroll
        for (int n = 0; n < 8; ++n) a3[n] = (f32x4){0.f, 0.f, 0.f, 0.f};
        #pragma unroll
        for (int ks = 0; ks < 2; ++ks) {
            int boff = (ks * 64 + kgrp * 16) ^ swa;
            bf16x8 af = *(const bf16x8*)(myb + arow * 64 + (boff >> 1));
            #pragma unroll
            for (int n = 0; n < 8; ++n) {
                bf16x8 bf = *(const bf16x8*)(sW3 + (size_t)(((n << 1) | ks) * 64 + lane) * 8);
                a3[n] = __builtin_amdgcn_mfma_f32_16x16x32_bf16(af, bf, a3[n], 0, 0, 0);
            }
        }
        // ---- bias + GELU -> U
        #pragma unroll
        for (int n = 0; n < 8; ++n) {
            float bias = bu1[n * 16 + arow];
            #pragma unroll
            for (int rr = 0; rr < 4; ++rr) {
                float vv = gelu(a3[n][rr] + bias);
                int hr = kgrp * 4 + rr;
                int boff = ((n * 16 + arow) * 2) ^ ((hr & 7) << 4);
                myb[hr * 128 + (boff >> 1)] = f2bf(vv);
            }
        }
        // ---- GEMM4 (16x128, K=128)
        f32x4 a4[8];
        #pragma unroll
        for (int n = 0; n < 8; ++n) a4[n] = (f32x4){0.f, 0.f, 0.f, 0.f};
        #pragma unroll
        for (int ks = 0; ks < 4; ++ks) {
            int boff = (ks * 64 + kgrp * 16) ^ swa;
            bf16x8 af = *(const bf16x8*)(myb + arow * 128 + (boff >> 1));
            #pragma unroll
            for (int n = 0; n < 8; ++n) {
                bf16x8 bf = *(const bf16x8*)(sW4 + (size_t)(((n << 2) | ks) * 64 + lane) * 8);
                a4[n] = __builtin_amdgcn_mfma_f32_16x16x32_bf16(af, bf, a4[n], 0, 0, 0);
            }
        }
        // ---- epilogue
        #pragma unroll
        for (int rr = 0; rr < 4; ++rr) {
            int gi2 = row0 + kgrp * 4 + rr;
            if (gi2 < NS) {
                #pragma unroll
                for (int n = 0; n < 8; ++n)
                    out_t[(size_t)gi2 * DD + n * 16 + arow] = a4[n][rr] + bu2[n * 16 + arow];
            }
        }
    }
}

extern "C" void kernel_launch(void* const* d_in, const int* in_sizes, int n_in,
                              void* d_out, int out_size, void* d_ws, size_t ws_size,
                              hipStream_t stream) {
    const float* x       = (const float*)d_in[0];
    const int*   indices = (const int*)d_in[1];
    const float* bd      = (const float*)d_in[2];
    const float* ln_d_g  = (const float*)d_in[3];
    const float* ln_d_b  = (const float*)d_in[4];
    const float* Wd1     = (const float*)d_in[5];
    const float* bd1     = (const float*)d_in[6];
    const float* Wd2     = (const float*)d_in[7];
    const float* bd2     = (const float*)d_in[8];
    const float* ln_u_g  = (const float*)d_in[9];
    const float* ln_u_b  = (const float*)d_in[10];
    const float* Wu1     = (const float*)d_in[11];
    const float* bu1     = (const float*)d_in[12];
    const float* Wu2     = (const float*)d_in[13];
    const float* bu2     = (const float*)d_in[14];
    float* out = (float*)d_out;

    // choose largest power-of-2 group size that fits ws
    int G = 8;
    while (G > 1) {
        size_t need = (size_t)G * NN * DD * 4 + (size_t)G * NN * CC * 4
                    + (size_t)NN * 8 * 4 + (size_t)8 * NS * 4 + TT * 4
                    + (size_t)9216 * 16 + 16 * 256;
        if (need <= ws_size) break;
        G >>= 1;
    }

    char* ws = (char*)d_ws;
    size_t o = 0;
    auto alloc = [&](size_t bytes) { char* p = ws + o; o = (o + bytes + 255) & ~(size_t)255; return p; };
    float* tables  = (float*)alloc((size_t)G * NN * DD * 4);
    float* h       = (float*)alloc((size_t)G * NN * CC * 4);
    int*   pernode = (int*)alloc((size_t)NN * 8 * 4);
    int*   lists   = (int*)alloc((size_t)8 * NS * 4);
    int*   cnts    = (int*)alloc(TT * 4);
    short* pW1     = (short*)alloc((size_t)4096 * 16);
    short* pW2     = (short*)alloc((size_t)2048 * 16);
    short* pW3     = (short*)alloc((size_t)1024 * 16);
    short* pW4     = (short*)alloc((size_t)2048 * 16);

    hipMemsetAsync(pernode, 0, (size_t)NN * 8 * 4, stream);
    hipMemsetAsync(cnts, 0, TT * 4, stream);

    prep_weights<<<16, 256, 0, stream>>>(Wd1, pW1, 4, 4096, 256);
    prep_weights<<<8, 256, 0, stream>>>(Wd2, pW2, 8, 2048, 64);
    prep_weights<<<4, 256, 0, stream>>>(Wu1, pW3, 2, 1024, 128);
    prep_weights<<<8, 256, 0, stream>>>(Wu2, pW4, 4, 2048, 128);

    for (int g0 = 0; g0 < TT; g0 += G) {
        const float* x_g   = x + (size_t)g0 * NS * DD;
        const int*   idx_g = indices + (size_t)g0 * NS;
        float*       out_g = out + (size_t)g0 * NS * DD;
        int*         cnt_g = cnts + g0;

        flag_kernel<<<(G * NS + 255) / 256, 256, 0, stream>>>(idx_g, pernode, G);
        zero_compact_kernel<<<(NN * 4 + 255) / 256, 256, 0, stream>>>(pernode, lists, cnt_g,
                                                                      tables, G);
        scatter_kernel<<<(G * NS * 32 + 255) / 256, 256, 0, stream>>>(x_g, idx_g, pernode,
                                                                      tables, G);
        mlp_d_kernel<<<256, 512, 0, stream>>>(tables, bd, ln_d_g, ln_d_b, pW1, pW2,
                                              bd1, bd2, lists, cnt_g, pernode, h, G);
        mlp_u_kernel<<<512, 512, 0, stream>>>(h, idx_g, ln_u_g, ln_u_b, pW3, pW4,
                                              bu1, bu2, out_g, G);
    }
}

// Round 4
// 850.815 us; speedup vs baseline: 2.7570x; 2.7570x over previous
//
#include <hip/hip_runtime.h>
#include <math.h>

#define NN 100000
#define DD 128
#define CC 64
#define TT 8
#define NS 50000

typedef __attribute__((ext_vector_type(4))) float f32x4;
typedef __attribute__((ext_vector_type(8))) short bf16x8;

__device__ __forceinline__ short f2bf(float f) {
    union { float f; unsigned u; } v; v.f = f;
    unsigned r = v.u + 0x7fffu + ((v.u >> 16) & 1u);
    return (short)(r >> 16);
}
// tanh-form GELU via hardware exp: max |diff| vs exact erf-GELU ~3e-3
__device__ __forceinline__ float gelu(float x) {
    float t = x + 0.044715f * x * x * x;
    return x / (1.0f + __expf(-1.5957691216f * t));
}

// ---------------- weight -> MFMA-fragment prearrange (bf16) ----------------
__global__ void prep_weights(const float* __restrict__ W, short* __restrict__ dst,
                             int KSTEPS, int total, int N) {
    int s = blockIdx.x * 256 + threadIdx.x;
    if (s >= total) return;
    int lane = s & 63;
    int ks = (s >> 6) % KSTEPS;
    int n = s / (64 * KSTEPS);
    int kb = ks * 32 + (lane >> 4) * 8;
    int col = n * 16 + (lane & 15);
    bf16x8 o;
    #pragma unroll
    for (int j = 0; j < 8; ++j) o[j] = f2bf(W[(size_t)(kb + j) * N + col]);
    *(bf16x8*)(dst + (size_t)s * 8) = o;
}

// ---------------- per-(node,g) contribution counts ----------------
__global__ void flag_kernel(const int* __restrict__ idx, int* __restrict__ pernode, int G) {
    int i = blockIdx.x * 256 + threadIdx.x;
    if (i >= G * NS) return;
    int g = i / NS;
    atomicAdd(&pernode[idx[i] * 8 + g], 1);
}

// ---------------- build per-g active lists (wave-aggregated atomics) --------
__global__ void compact_kernel(const int* __restrict__ pernode,
                               int* __restrict__ lists, int* __restrict__ cnts) {
    int g = blockIdx.y;
    int node = blockIdx.x * 256 + threadIdx.x;
    bool active = (node < NN) && (pernode[node * 8 + g] > 0);
    unsigned long long m = __ballot(active);
    int lane = threadIdx.x & 63;
    int rank = __popcll(m & ((1ull << lane) - 1ull));
    int cnt = __popcll(m);
    int base = 0;
    if (lane == 0 && cnt > 0) base = atomicAdd(&cnts[g], cnt);
    base = __shfl(base, 0);
    if (active) lists[(size_t)g * NS + base + rank] = node;
}

// ---------------- zero only multi-contributor rows (coalesced) --------------
__global__ void zero_kernel(const int* __restrict__ pernode,
                            const int* __restrict__ lists, const int* __restrict__ cnts,
                            float* __restrict__ tables) {
    int g = blockIdx.y;
    int cnt = cnts[g];
    int total = cnt * 32;
    float4 z = {0.f, 0.f, 0.f, 0.f};
    for (int t = blockIdx.x * 256 + threadIdx.x; t < total; t += gridDim.x * 256) {
        int row = t >> 5, l = t & 31;
        int node = lists[(size_t)g * NS + row];
        if (pernode[node * 8 + g] < 2) continue;   // count==1 rows are plain-stored
        ((float4*)(tables + (size_t)g * (NN * DD) + (size_t)node * DD))[l] = z;
    }
}

// ---------------- scatter: plain store when unique, atomics otherwise -------
__global__ void scatter_kernel(const float* __restrict__ x, const int* __restrict__ idx,
                               const int* __restrict__ pernode,
                               float* __restrict__ tables, int G) {
    int tid = blockIdx.x * 256 + threadIdx.x;  // G*NS*32
    int i = tid >> 5;
    if (i >= G * NS) return;
    int g = i / NS;
    int d4 = (tid & 31) * 4;
    int node = idx[i];
    float4 v = *(const float4*)(x + (size_t)i * DD + d4);
    float* dst = tables + (size_t)g * (NN * DD) + (size_t)node * DD + d4;
    if (pernode[node * 8 + g] == 1) {
        *(float4*)dst = v;
    } else {
        atomicAdd(dst + 0, v.x); atomicAdd(dst + 1, v.y);
        atomicAdd(dst + 2, v.z); atomicAdd(dst + 3, v.w);
    }
}

// ---------------- fused mlp_d over all groups: LN -> G1+GELU -> G2 ----------
// 512 threads = 8 waves, 16 rows/wave, strip=128 rows. LDS 160KB -> 1 block/CU.
__global__ __launch_bounds__(512, 2) void mlp_d_kernel(
    const float* __restrict__ tables, const float* __restrict__ bd,
    const float* __restrict__ lng, const float* __restrict__ lnb,
    const short* __restrict__ pW1, const short* __restrict__ pW2,
    const float* __restrict__ bd1, const float* __restrict__ bd2,
    const int* __restrict__ lists, const int* __restrict__ cnts,
    float* __restrict__ h, int G) {
    __shared__ short sW1[4096 * 8];
    __shared__ short sW2[2048 * 8];
    __shared__ short sAH[8][4096];  // per-wave: A [16][128] in [0,2048), H [16][256] in [0,4096)

    const int tid = threadIdx.x;
    for (int s = tid; s < 4096; s += 512)
        *(bf16x8*)(sW1 + s * 8) = *(const bf16x8*)(pW1 + (size_t)s * 8);
    for (int s = tid; s < 2048; s += 512)
        *(bf16x8*)(sW2 + s * 8) = *(const bf16x8*)(pW2 + (size_t)s * 8);
    __syncthreads();

    const int wave = tid >> 6, lane = tid & 63;
    short* myb = sAH[wave];
    const int arow = lane & 15;
    const int kgrp = lane >> 4;
    const int swa = (arow & 7) << 4;
    const int MAXS = (NS + 127) / 128;   // 391

    for (int w = blockIdx.x; w < G * MAXS; w += gridDim.x) {
        const int g = w % G;
        const int strip = w / G;
        const int nrows = cnts[g];
        if (strip * 128 >= nrows) continue;
        const float* table = tables + (size_t)g * (NN * DD);
        const int* list = lists + (size_t)g * NS;
        float* h_t = h + (size_t)g * (NN * CC);
        const int row0 = strip * 128 + wave * 16;

        // ---- LN (4 lanes/row, 32 cols/lane) -> swizzled bf16 A
        {
            const int r = lane >> 2;
            const int c0 = (lane & 3) * 32;
            const int gi = row0 + r;
            const int node = list[gi < nrows ? gi : (nrows - 1)];
            const float* tp = table + (size_t)node * DD + c0;
            const float* bp = bd + (size_t)node * DD + c0;
            float v[32];
            float s1 = 0.f;
            #pragma unroll
            for (int j = 0; j < 8; ++j) {
                float4 a = ((const float4*)tp)[j];
                float4 c = ((const float4*)bp)[j];
                v[j * 4 + 0] = a.x + c.x; v[j * 4 + 1] = a.y + c.y;
                v[j * 4 + 2] = a.z + c.z; v[j * 4 + 3] = a.w + c.w;
                s1 += v[j * 4 + 0] + v[j * 4 + 1] + v[j * 4 + 2] + v[j * 4 + 3];
            }
            s1 += __shfl_xor(s1, 1); s1 += __shfl_xor(s1, 2);
            float mu = s1 * 0.0078125f;
            float s2 = 0.f;
            #pragma unroll
            for (int j = 0; j < 32; ++j) { float d = v[j] - mu; s2 += d * d; }
            s2 += __shfl_xor(s2, 1); s2 += __shfl_xor(s2, 2);
            float rs = rsqrtf(s2 * 0.0078125f + 1e-5f);
            short ov[32];
            #pragma unroll
            for (int j = 0; j < 8; ++j) {
                float4 gv = ((const float4*)(lng + c0))[j];
                float4 bv = ((const float4*)(lnb + c0))[j];
                ov[j * 4 + 0] = f2bf((v[j * 4 + 0] - mu) * rs * gv.x + bv.x);
                ov[j * 4 + 1] = f2bf((v[j * 4 + 1] - mu) * rs * gv.y + bv.y);
                ov[j * 4 + 2] = f2bf((v[j * 4 + 2] - mu) * rs * gv.z + bv.z);
                ov[j * 4 + 3] = f2bf((v[j * 4 + 3] - mu) * rs * gv.w + bv.w);
            }
            const int swr = (r & 7) << 4;
            #pragma unroll
            for (int q = 0; q < 4; ++q) {
                int boff = (c0 * 2 + q * 16) ^ swr;
                *(bf16x8*)(myb + r * 128 + (boff >> 1)) = *(bf16x8*)(ov + q * 8);
            }
        }
        // ---- GEMM1 (16x256, K=128)
        f32x4 acc[16];
        #pragma unroll
        for (int n = 0; n < 16; ++n) acc[n] = (f32x4){0.f, 0.f, 0.f, 0.f};
        #pragma unroll
        for (int ks = 0; ks < 4; ++ks) {
            int boff = (ks * 64 + kgrp * 16) ^ swa;
            bf16x8 af = *(const bf16x8*)(myb + arow * 128 + (boff >> 1));
            #pragma unroll
            for (int n = 0; n < 16; ++n) {
                bf16x8 bf = *(const bf16x8*)(sW1 + (size_t)(((n << 2) | ks) * 64 + lane) * 8);
                acc[n] = __builtin_amdgcn_mfma_f32_16x16x32_bf16(af, bf, acc[n], 0, 0, 0);
            }
        }
        // ---- bias + GELU -> swizzled bf16 H
        #pragma unroll
        for (int n = 0; n < 16; ++n) {
            float bias = bd1[n * 16 + arow];
            #pragma unroll
            for (int rr = 0; rr < 4; ++rr) {
                float vv = gelu(acc[n][rr] + bias);
                int hr = kgrp * 4 + rr;
                int boff = ((n * 16 + arow) * 2) ^ ((hr & 7) << 4);
                myb[hr * 256 + (boff >> 1)] = f2bf(vv);
            }
        }
        // ---- GEMM2 (16x64, K=256)
        f32x4 acc2[4];
        #pragma unroll
        for (int n = 0; n < 4; ++n) acc2[n] = (f32x4){0.f, 0.f, 0.f, 0.f};
        #pragma unroll
        for (int ks = 0; ks < 8; ++ks) {
            int boff = (ks * 64 + kgrp * 16) ^ swa;
            bf16x8 af = *(const bf16x8*)(myb + arow * 256 + (boff >> 1));
            #pragma unroll
            for (int n = 0; n < 4; ++n) {
                bf16x8 bf = *(const bf16x8*)(sW2 + (size_t)(((n << 3) | ks) * 64 + lane) * 8);
                acc2[n] = __builtin_amdgcn_mfma_f32_16x16x32_bf16(af, bf, acc2[n], 0, 0, 0);
            }
        }
        // ---- epilogue: h[node]
        #pragma unroll
        for (int rr = 0; rr < 4; ++rr) {
            int gi2 = row0 + kgrp * 4 + rr;
            if (gi2 < nrows) {
                int node2 = list[gi2];
                #pragma unroll
                for (int n = 0; n < 4; ++n)
                    h_t[(size_t)node2 * CC + n * 16 + arow] = acc2[n][rr] + bd2[n * 16 + arow];
            }
        }
    }
}

// ---------------- fused mlp_u over all groups -------------------------------
__global__ __launch_bounds__(512, 4) void mlp_u_kernel(
    const float* __restrict__ h, const int* __restrict__ idx,
    const float* __restrict__ lng, const float* __restrict__ lnb,
    const short* __restrict__ pW3, const short* __restrict__ pW4,
    const float* __restrict__ bu1, const float* __restrict__ bu2,
    float* __restrict__ out, int G) {
    __shared__ short sW3[1024 * 8];
    __shared__ short sW4[2048 * 8];
    __shared__ short sAU[8][2048];

    const int tid = threadIdx.x;
    for (int s = tid; s < 1024; s += 512)
        *(bf16x8*)(sW3 + s * 8) = *(const bf16x8*)(pW3 + (size_t)s * 8);
    for (int s = tid; s < 2048; s += 512)
        *(bf16x8*)(sW4 + s * 8) = *(const bf16x8*)(pW4 + (size_t)s * 8);
    __syncthreads();

    const int wave = tid >> 6, lane = tid & 63;
    short* myb = sAU[wave];
    const int arow = lane & 15;
    const int kgrp = lane >> 4;
    const int swa = (arow & 7) << 4;
    const int MAXS = (NS + 127) / 128;   // 391

    for (int w = blockIdx.x; w < G * MAXS; w += gridDim.x) {
        const int g = w % G;
        const int strip = w / G;
        const int* idx_t = idx + (size_t)g * NS;
        const float* h_t = h + (size_t)g * (NN * CC);
        float* out_t = out + (size_t)g * NS * DD;
        const int row0 = strip * 128 + wave * 16;

        // ---- gather + LN (4 lanes/row, 16 cols/lane)
        {
            const int r = lane >> 2;
            const int c0 = (lane & 3) * 16;
            const int gi = row0 + r;
            const int srow = gi < NS ? gi : (NS - 1);
            const int node = idx_t[srow];
            const float* hp = h_t + (size_t)node * CC + c0;
            float v[16];
            float s1 = 0.f;
            #pragma unroll
            for (int j = 0; j < 4; ++j) {
                float4 a = ((const float4*)hp)[j];
                v[j * 4 + 0] = a.x; v[j * 4 + 1] = a.y; v[j * 4 + 2] = a.z; v[j * 4 + 3] = a.w;
                s1 += a.x + a.y + a.z + a.w;
            }
            s1 += __shfl_xor(s1, 1); s1 += __shfl_xor(s1, 2);
            float mu = s1 * 0.015625f;
            float s2 = 0.f;
            #pragma unroll
            for (int j = 0; j < 16; ++j) { float d = v[j] - mu; s2 += d * d; }
            s2 += __shfl_xor(s2, 1); s2 += __shfl_xor(s2, 2);
            float rs = rsqrtf(s2 * 0.015625f + 1e-5f);
            short ov[16];
            #pragma unroll
            for (int j = 0; j < 4; ++j) {
                float4 gv = ((const float4*)(lng + c0))[j];
                float4 bv = ((const float4*)(lnb + c0))[j];
                ov[j * 4 + 0] = f2bf((v[j * 4 + 0] - mu) * rs * gv.x + bv.x);
                ov[j * 4 + 1] = f2bf((v[j * 4 + 1] - mu) * rs * gv.y + bv.y);
                ov[j * 4 + 2] = f2bf((v[j * 4 + 2] - mu) * rs * gv.z + bv.z);
                ov[j * 4 + 3] = f2bf((v[j * 4 + 3] - mu) * rs * gv.w + bv.w);
            }
            const int swr = (r & 7) << 4;
            #pragma unroll
            for (int q = 0; q < 2; ++q) {
                int boff = (c0 * 2 + q * 16) ^ swr;
                *(bf16x8*)(myb + r * 64 + (boff >> 1)) = *(bf16x8*)(ov + q * 8);
            }
        }
        // ---- GEMM3 (16x128, K=64)
        f32x4 a3[8];
        #pragma unroll
        for (int n = 0; n < 8; ++n) a3[n] = (f32x4){0.f, 0.f, 0.f, 0.f};
        #pragma unroll
        for (int ks = 0; ks < 2; ++ks) {
            int boff = (ks * 64 + kgrp * 16) ^ swa;
            bf16x8 af = *(const bf16x8*)(myb + arow * 64 + (boff >> 1));
            #pragma unroll
            for (int n = 0; n < 8; ++n) {
                bf16x8 bf = *(const bf16x8*)(sW3 + (size_t)(((n << 1) | ks) * 64 + lane) * 8);
                a3[n] = __builtin_amdgcn_mfma_f32_16x16x32_bf16(af, bf, a3[n], 0, 0, 0);
            }
        }
        // ---- bias + GELU -> U
        #pragma unroll
        for (int n = 0; n < 8; ++n) {
            float bias = bu1[n * 16 + arow];
            #pragma unroll
            for (int rr = 0; rr < 4; ++rr) {
                float vv = gelu(a3[n][rr] + bias);
                int hr = kgrp * 4 + rr;
                int boff = ((n * 16 + arow) * 2) ^ ((hr & 7) << 4);
                myb[hr * 128 + (boff >> 1)] = f2bf(vv);
            }
        }
        // ---- GEMM4 (16x128, K=128)
        f32x4 a4[8];
        #pragma unroll
        for (int n = 0; n < 8; ++n) a4[n] = (f32x4){0.f, 0.f, 0.f, 0.f};
        #pragma unroll
        for (int ks = 0; ks < 4; ++ks) {
            int boff = (ks * 64 + kgrp * 16) ^ swa;
            bf16x8 af = *(const bf16x8*)(myb + arow * 128 + (boff >> 1));
            #pragma unroll
            for (int n = 0; n < 8; ++n) {
                bf16x8 bf = *(const bf16x8*)(sW4 + (size_t)(((n << 2) | ks) * 64 + lane) * 8);
                a4[n] = __builtin_amdgcn_mfma_f32_16x16x32_bf16(af, bf, a4[n], 0, 0, 0);
            }
        }
        // ---- epilogue
        #pragma unroll
        for (int rr = 0; rr < 4; ++rr) {
            int gi2 = row0 + kgrp * 4 + rr;
            if (gi2 < NS) {
                #pragma unroll
                for (int n = 0; n < 8; ++n)
                    out_t[(size_t)gi2 * DD + n * 16 + arow] = a4[n][rr] + bu2[n * 16 + arow];
            }
        }
    }
}

extern "C" void kernel_launch(void* const* d_in, const int* in_sizes, int n_in,
                              void* d_out, int out_size, void* d_ws, size_t ws_size,
                              hipStream_t stream) {
    const float* x       = (const float*)d_in[0];
    const int*   indices = (const int*)d_in[1];
    const float* bd      = (const float*)d_in[2];
    const float* ln_d_g  = (const float*)d_in[3];
    const float* ln_d_b  = (const float*)d_in[4];
    const float* Wd1     = (const float*)d_in[5];
    const float* bd1     = (const float*)d_in[6];
    const float* Wd2     = (const float*)d_in[7];
    const float* bd2     = (const float*)d_in[8];
    const float* ln_u_g  = (const float*)d_in[9];
    const float* ln_u_b  = (const float*)d_in[10];
    const float* Wu1     = (const float*)d_in[11];
    const float* bu1     = (const float*)d_in[12];
    const float* Wu2     = (const float*)d_in[13];
    const float* bu2     = (const float*)d_in[14];
    float* out = (float*)d_out;

    // choose largest power-of-2 group size that fits ws
    int G = 8;
    while (G > 1) {
        size_t need = (size_t)G * NN * DD * 4 + (size_t)G * NN * CC * 4
                    + (size_t)NN * 8 * 4 + (size_t)8 * NS * 4 + TT * 4
                    + (size_t)9216 * 16 + 16 * 256;
        if (need <= ws_size) break;
        G >>= 1;
    }

    char* ws = (char*)d_ws;
    size_t o = 0;
    auto alloc = [&](size_t bytes) { char* p = ws + o; o = (o + bytes + 255) & ~(size_t)255; return p; };
    float* tables  = (float*)alloc((size_t)G * NN * DD * 4);
    float* h       = (float*)alloc((size_t)G * NN * CC * 4);
    int*   pernode = (int*)alloc((size_t)NN * 8 * 4);
    int*   lists   = (int*)alloc((size_t)8 * NS * 4);
    int*   cnts    = (int*)alloc(TT * 4);
    short* pW1     = (short*)alloc((size_t)4096 * 16);
    short* pW2     = (short*)alloc((size_t)2048 * 16);
    short* pW3     = (short*)alloc((size_t)1024 * 16);
    short* pW4     = (short*)alloc((size_t)2048 * 16);

    hipMemsetAsync(pernode, 0, (size_t)NN * 8 * 4, stream);
    hipMemsetAsync(cnts, 0, TT * 4, stream);

    prep_weights<<<16, 256, 0, stream>>>(Wd1, pW1, 4, 4096, 256);
    prep_weights<<<8, 256, 0, stream>>>(Wd2, pW2, 8, 2048, 64);
    prep_weights<<<4, 256, 0, stream>>>(Wu1, pW3, 2, 1024, 128);
    prep_weights<<<8, 256, 0, stream>>>(Wu2, pW4, 4, 2048, 128);

    for (int g0 = 0; g0 < TT; g0 += G) {
        const float* x_g   = x + (size_t)g0 * NS * DD;
        const int*   idx_g = indices + (size_t)g0 * NS;
        float*       out_g = out + (size_t)g0 * NS * DD;
        int*         cnt_g = cnts + g0;

        flag_kernel<<<(G * NS + 255) / 256, 256, 0, stream>>>(idx_g, pernode, G);
        compact_kernel<<<dim3((NN + 255) / 256, G), 256, 0, stream>>>(pernode, lists, cnt_g);
        zero_kernel<<<dim3(256, G), 256, 0, stream>>>(pernode, lists, cnt_g, tables);
        scatter_kernel<<<(G * NS * 32 + 255) / 256, 256, 0, stream>>>(x_g, idx_g, pernode,
                                                                      tables, G);
        mlp_d_kernel<<<256, 512, 0, stream>>>(tables, bd, ln_d_g, ln_d_b, pW1, pW2,
                                              bd1, bd2, lists, cnt_g, h, G);
        mlp_u_kernel<<<512, 512, 0, stream>>>(h, idx_g, ln_u_g, ln_u_b, pW3, pW4,
                                              bu1, bu2, out_g, G);
    }
}

// Round 5
// 562.294 us; speedup vs baseline: 4.1717x; 1.5131x over previous
//
#include <hip/hip_runtime.h>
#include <math.h>

#define NN 100000
#define DD 128
#define CC 64
#define TT 8
#define NS 50000

typedef __attribute__((ext_vector_type(4))) float f32x4;
typedef __attribute__((ext_vector_type(8))) short bf16x8;

__device__ __forceinline__ short f2bf(float f) {
    union { float f; unsigned u; } v; v.f = f;
    unsigned r = v.u + 0x7fffu + ((v.u >> 16) & 1u);
    return (short)(r >> 16);
}
// tanh-form GELU via hardware exp: max |diff| vs exact erf-GELU ~3e-3
__device__ __forceinline__ float gelu(float x) {
    float t = x + 0.044715f * x * x * x;
    return x / (1.0f + __expf(-1.5957691216f * t));
}

// ---------------- weight -> MFMA-fragment prearrange (bf16) ----------------
__global__ void prep_weights(const float* __restrict__ W, short* __restrict__ dst,
                             int KSTEPS, int total, int N) {
    int s = blockIdx.x * 256 + threadIdx.x;
    if (s >= total) return;
    int lane = s & 63;
    int ks = (s >> 6) % KSTEPS;
    int n = s / (64 * KSTEPS);
    int kb = ks * 32 + (lane >> 4) * 8;
    int col = n * 16 + (lane & 15);
    bf16x8 o;
    #pragma unroll
    for (int j = 0; j < 8; ++j) o[j] = f2bf(W[(size_t)(kb + j) * N + col]);
    *(bf16x8*)(dst + (size_t)s * 8) = o;
}

// ---------------- per-(node,g) contribution counts ----------------
__global__ void flag_kernel(const int* __restrict__ idx, int* __restrict__ pernode, int G) {
    int i = blockIdx.x * 256 + threadIdx.x;
    if (i >= G * NS) return;
    int g = i / NS;
    atomicAdd(&pernode[idx[i] * 8 + g], 1);
}

// ------- build per-g active lists + contributor offsets (wave-aggregated) ---
__global__ void compact_kernel(const int* __restrict__ pernode, int* __restrict__ cursor,
                               int* __restrict__ lists, int* __restrict__ cnts,
                               int* __restrict__ alloc) {
    int g = blockIdx.y;
    int node = blockIdx.x * 256 + threadIdx.x;
    int c = (node < NN) ? pernode[node * 8 + g] : 0;
    bool active = c > 0;
    int lane = threadIdx.x & 63;
    // active-list slot via ballot
    unsigned long long m = __ballot(active);
    int rank = __popcll(m & ((1ull << lane) - 1ull));
    int nact = __popcll(m);
    int lbase = 0;
    if (lane == 0 && nact > 0) lbase = atomicAdd(&cnts[g], nact);
    lbase = __shfl(lbase, 0);
    if (active) lists[(size_t)g * NS + lbase + rank] = node;
    // contributor-offset via wave inclusive scan of counts
    int pre = c;
    #pragma unroll
    for (int off = 1; off <= 32; off <<= 1) {
        int t = __shfl_up(pre, off);
        if (lane >= off) pre += t;
    }
    int wtot = __shfl(pre, 63);
    int obase = 0;
    if (lane == 0 && wtot > 0) obase = atomicAdd(&alloc[g], wtot);
    obase = __shfl(obase, 0);
    if (active) cursor[node * 8 + g] = obase + (pre - c);
}

// ---------------- fill contributor positions (counting sort) ----------------
__global__ void fill_kernel(const int* __restrict__ idx, int* __restrict__ cursor,
                            int* __restrict__ positions, int G) {
    int i = blockIdx.x * 256 + threadIdx.x;
    if (i >= G * NS) return;
    int g = i / NS, s = i - g * NS;
    int node = idx[i];
    int p = atomicAdd(&cursor[node * 8 + g], 1);
    positions[(size_t)g * NS + p] = s;
}

// ---------------- fused mlp_d: aggregate-from-x -> LN -> G1+GELU -> G2 ------
// 512 threads = 8 waves, 16 rows/wave, strip=128 rows. LDS 160KB -> 1 block/CU.
__global__ __launch_bounds__(512, 2) void mlp_d_kernel(
    const float* __restrict__ x, const float* __restrict__ bd,
    const float* __restrict__ lng, const float* __restrict__ lnb,
    const short* __restrict__ pW1, const short* __restrict__ pW2,
    const float* __restrict__ bd1, const float* __restrict__ bd2,
    const int* __restrict__ lists, const int* __restrict__ cnts,
    const int* __restrict__ pernode, const int* __restrict__ cursor,
    const int* __restrict__ positions,
    float* __restrict__ h, int G) {
    __shared__ short sW1[4096 * 8];
    __shared__ short sW2[2048 * 8];
    __shared__ short sAH[8][4096];  // per-wave: A [16][128] in [0,2048), H [16][256] in [0,4096)

    const int tid = threadIdx.x;
    for (int s = tid; s < 4096; s += 512)
        *(bf16x8*)(sW1 + s * 8) = *(const bf16x8*)(pW1 + (size_t)s * 8);
    for (int s = tid; s < 2048; s += 512)
        *(bf16x8*)(sW2 + s * 8) = *(const bf16x8*)(pW2 + (size_t)s * 8);
    __syncthreads();

    const int wave = tid >> 6, lane = tid & 63;
    short* myb = sAH[wave];
    const int arow = lane & 15;
    const int kgrp = lane >> 4;
    const int swa = (arow & 7) << 4;
    const int MAXS = (NS + 127) / 128;   // 391

    for (int w = blockIdx.x; w < G * MAXS; w += gridDim.x) {
        const int g = w % G;
        const int strip = w / G;
        const int nrows = cnts[g];
        if (strip * 128 >= nrows) continue;
        const int* list = lists + (size_t)g * NS;
        const int* pos_g = positions + (size_t)g * NS;
        const float* x_g = x + (size_t)g * NS * DD;
        float* h_t = h + (size_t)g * (NN * CC);
        const int row0 = strip * 128 + wave * 16;

        // ---- aggregate contributors + bd, then LN (4 lanes/row, 32 cols/lane)
        {
            const int r = lane >> 2;
            const int c0 = (lane & 3) * 32;
            const int gi = row0 + r;
            const int node = list[gi < nrows ? gi : (nrows - 1)];
            const int cnt = pernode[node * 8 + g];
            const int end = cursor[node * 8 + g];      // offset+cnt after fill
            const int off = end - cnt;
            float v[32];
            {
                const float* bp = bd + (size_t)node * DD + c0;
                #pragma unroll
                for (int j = 0; j < 8; ++j) {
                    float4 c = ((const float4*)bp)[j];
                    v[j * 4 + 0] = c.x; v[j * 4 + 1] = c.y;
                    v[j * 4 + 2] = c.z; v[j * 4 + 3] = c.w;
                }
            }
            for (int j = 0; j < cnt; ++j) {
                int s = pos_g[off + j];
                const float* xp = x_g + (size_t)s * DD + c0;
                #pragma unroll
                for (int q = 0; q < 8; ++q) {
                    float4 a = ((const float4*)xp)[q];
                    v[q * 4 + 0] += a.x; v[q * 4 + 1] += a.y;
                    v[q * 4 + 2] += a.z; v[q * 4 + 3] += a.w;
                }
            }
            float s1 = 0.f;
            #pragma unroll
            for (int j = 0; j < 32; ++j) s1 += v[j];
            s1 += __shfl_xor(s1, 1); s1 += __shfl_xor(s1, 2);
            float mu = s1 * 0.0078125f;
            float s2 = 0.f;
            #pragma unroll
            for (int j = 0; j < 32; ++j) { float d = v[j] - mu; s2 += d * d; }
            s2 += __shfl_xor(s2, 1); s2 += __shfl_xor(s2, 2);
            float rs = rsqrtf(s2 * 0.0078125f + 1e-5f);
            short ov[32];
            #pragma unroll
            for (int j = 0; j < 8; ++j) {
                float4 gv = ((const float4*)(lng + c0))[j];
                float4 bv = ((const float4*)(lnb + c0))[j];
                ov[j * 4 + 0] = f2bf((v[j * 4 + 0] - mu) * rs * gv.x + bv.x);
                ov[j * 4 + 1] = f2bf((v[j * 4 + 1] - mu) * rs * gv.y + bv.y);
                ov[j * 4 + 2] = f2bf((v[j * 4 + 2] - mu) * rs * gv.z + bv.z);
                ov[j * 4 + 3] = f2bf((v[j * 4 + 3] - mu) * rs * gv.w + bv.w);
            }
            const int swr = (r & 7) << 4;
            #pragma unroll
            for (int q = 0; q < 4; ++q) {
                int boff = (c0 * 2 + q * 16) ^ swr;
                *(bf16x8*)(myb + r * 128 + (boff >> 1)) = *(bf16x8*)(ov + q * 8);
            }
        }
        // ---- GEMM1 (16x256, K=128)
        f32x4 acc[16];
        #pragma unroll
        for (int n = 0; n < 16; ++n) acc[n] = (f32x4){0.f, 0.f, 0.f, 0.f};
        #pragma unroll
        for (int ks = 0; ks < 4; ++ks) {
            int boff = (ks * 64 + kgrp * 16) ^ swa;
            bf16x8 af = *(const bf16x8*)(myb + arow * 128 + (boff >> 1));
            #pragma unroll
            for (int n = 0; n < 16; ++n) {
                bf16x8 bf = *(const bf16x8*)(sW1 + (size_t)(((n << 2) | ks) * 64 + lane) * 8);
                acc[n] = __builtin_amdgcn_mfma_f32_16x16x32_bf16(af, bf, acc[n], 0, 0, 0);
            }
        }
        // ---- bias + GELU -> swizzled bf16 H
        #pragma unroll
        for (int n = 0; n < 16; ++n) {
            float bias = bd1[n * 16 + arow];
            #pragma unroll
            for (int rr = 0; rr < 4; ++rr) {
                float vv = gelu(acc[n][rr] + bias);
                int hr = kgrp * 4 + rr;
                int boff = ((n * 16 + arow) * 2) ^ ((hr & 7) << 4);
                myb[hr * 256 + (boff >> 1)] = f2bf(vv);
            }
        }
        // ---- GEMM2 (16x64, K=256)
        f32x4 acc2[4];
        #pragma unroll
        for (int n = 0; n < 4; ++n) acc2[n] = (f32x4){0.f, 0.f, 0.f, 0.f};
        #pragma unroll
        for (int ks = 0; ks < 8; ++ks) {
            int boff = (ks * 64 + kgrp * 16) ^ swa;
            bf16x8 af = *(const bf16x8*)(myb + arow * 256 + (boff >> 1));
            #pragma unroll
            for (int n = 0; n < 4; ++n) {
                bf16x8 bf = *(const bf16x8*)(sW2 + (size_t)(((n << 3) | ks) * 64 + lane) * 8);
                acc2[n] = __builtin_amdgcn_mfma_f32_16x16x32_bf16(af, bf, acc2[n], 0, 0, 0);
            }
        }
        // ---- epilogue: h[node]
        #pragma unroll
        for (int rr = 0; rr < 4; ++rr) {
            int gi2 = row0 + kgrp * 4 + rr;
            if (gi2 < nrows) {
                int node2 = list[gi2];
                #pragma unroll
                for (int n = 0; n < 4; ++n)
                    h_t[(size_t)node2 * CC + n * 16 + arow] = acc2[n][rr] + bd2[n * 16 + arow];
            }
        }
    }
}

// ---------------- fused mlp_u over all groups -------------------------------
__global__ __launch_bounds__(512, 4) void mlp_u_kernel(
    const float* __restrict__ h, const int* __restrict__ idx,
    const float* __restrict__ lng, const float* __restrict__ lnb,
    const short* __restrict__ pW3, const short* __restrict__ pW4,
    const float* __restrict__ bu1, const float* __restrict__ bu2,
    float* __restrict__ out, int G) {
    __shared__ short sW3[1024 * 8];
    __shared__ short sW4[2048 * 8];
    __shared__ short sAU[8][2048];

    const int tid = threadIdx.x;
    for (int s = tid; s < 1024; s += 512)
        *(bf16x8*)(sW3 + s * 8) = *(const bf16x8*)(pW3 + (size_t)s * 8);
    for (int s = tid; s < 2048; s += 512)
        *(bf16x8*)(sW4 + s * 8) = *(const bf16x8*)(pW4 + (size_t)s * 8);
    __syncthreads();

    const int wave = tid >> 6, lane = tid & 63;
    short* myb = sAU[wave];
    const int arow = lane & 15;
    const int kgrp = lane >> 4;
    const int swa = (arow & 7) << 4;
    const int MAXS = (NS + 127) / 128;   // 391

    for (int w = blockIdx.x; w < G * MAXS; w += gridDim.x) {
        const int g = w % G;
        const int strip = w / G;
        const int* idx_t = idx + (size_t)g * NS;
        const float* h_t = h + (size_t)g * (NN * CC);
        float* out_t = out + (size_t)g * NS * DD;
        const int row0 = strip * 128 + wave * 16;

        // ---- gather + LN (4 lanes/row, 16 cols/lane)
        {
            const int r = lane >> 2;
            const int c0 = (lane & 3) * 16;
            const int gi = row0 + r;
            const int srow = gi < NS ? gi : (NS - 1);
            const int node = idx_t[srow];
            const float* hp = h_t + (size_t)node * CC + c0;
            float v[16];
            float s1 = 0.f;
            #pragma unroll
            for (int j = 0; j < 4; ++j) {
                float4 a = ((const float4*)hp)[j];
                v[j * 4 + 0] = a.x; v[j * 4 + 1] = a.y; v[j * 4 + 2] = a.z; v[j * 4 + 3] = a.w;
                s1 += a.x + a.y + a.z + a.w;
            }
            s1 += __shfl_xor(s1, 1); s1 += __shfl_xor(s1, 2);
            float mu = s1 * 0.015625f;
            float s2 = 0.f;
            #pragma unroll
            for (int j = 0; j < 16; ++j) { float d = v[j] - mu; s2 += d * d; }
            s2 += __shfl_xor(s2, 1); s2 += __shfl_xor(s2, 2);
            float rs = rsqrtf(s2 * 0.015625f + 1e-5f);
            short ov[16];
            #pragma unroll
            for (int j = 0; j < 4; ++j) {
                float4 gv = ((const float4*)(lng + c0))[j];
                float4 bv = ((const float4*)(lnb + c0))[j];
                ov[j * 4 + 0] = f2bf((v[j * 4 + 0] - mu) * rs * gv.x + bv.x);
                ov[j * 4 + 1] = f2bf((v[j * 4 + 1] - mu) * rs * gv.y + bv.y);
                ov[j * 4 + 2] = f2bf((v[j * 4 + 2] - mu) * rs * gv.z + bv.z);
                ov[j * 4 + 3] = f2bf((v[j * 4 + 3] - mu) * rs * gv.w + bv.w);
            }
            const int swr = (r & 7) << 4;
            #pragma unroll
            for (int q = 0; q < 2; ++q) {
                int boff = (c0 * 2 + q * 16) ^ swr;
                *(bf16x8*)(myb + r * 64 + (boff >> 1)) = *(bf16x8*)(ov + q * 8);
            }
        }
        // ---- GEMM3 (16x128, K=64)
        f32x4 a3[8];
        #pragma unroll
        for (int n = 0; n < 8; ++n) a3[n] = (f32x4){0.f, 0.f, 0.f, 0.f};
        #pragma unroll
        for (int ks = 0; ks < 2; ++ks) {
            int boff = (ks * 64 + kgrp * 16) ^ swa;
            bf16x8 af = *(const bf16x8*)(myb + arow * 64 + (boff >> 1));
            #pragma unroll
            for (int n = 0; n < 8; ++n) {
                bf16x8 bf = *(const bf16x8*)(sW3 + (size_t)(((n << 1) | ks) * 64 + lane) * 8);
                a3[n] = __builtin_amdgcn_mfma_f32_16x16x32_bf16(af, bf, a3[n], 0, 0, 0);
            }
        }
        // ---- bias + GELU -> U
        #pragma unroll
        for (int n = 0; n < 8; ++n) {
            float bias = bu1[n * 16 + arow];
            #pragma unroll
            for (int rr = 0; rr < 4; ++rr) {
                float vv = gelu(a3[n][rr] + bias);
                int hr = kgrp * 4 + rr;
                int boff = ((n * 16 + arow) * 2) ^ ((hr & 7) << 4);
                myb[hr * 128 + (boff >> 1)] = f2bf(vv);
            }
        }
        // ---- GEMM4 (16x128, K=128)
        f32x4 a4[8];
        #pragma unroll
        for (int n = 0; n < 8; ++n) a4[n] = (f32x4){0.f, 0.f, 0.f, 0.f};
        #pragma unroll
        for (int ks = 0; ks < 4; ++ks) {
            int boff = (ks * 64 + kgrp * 16) ^ swa;
            bf16x8 af = *(const bf16x8*)(myb + arow * 128 + (boff >> 1));
            #pragma unroll
            for (int n = 0; n < 8; ++n) {
                bf16x8 bf = *(const bf16x8*)(sW4 + (size_t)(((n << 2) | ks) * 64 + lane) * 8);
                a4[n] = __builtin_amdgcn_mfma_f32_16x16x32_bf16(af, bf, a4[n], 0, 0, 0);
            }
        }
        // ---- epilogue
        #pragma unroll
        for (int rr = 0; rr < 4; ++rr) {
            int gi2 = row0 + kgrp * 4 + rr;
            if (gi2 < NS) {
                #pragma unroll
                for (int n = 0; n < 8; ++n)
                    out_t[(size_t)gi2 * DD + n * 16 + arow] = a4[n][rr] + bu2[n * 16 + arow];
            }
        }
    }
}

extern "C" void kernel_launch(void* const* d_in, const int* in_sizes, int n_in,
                              void* d_out, int out_size, void* d_ws, size_t ws_size,
                              hipStream_t stream) {
    const float* x       = (const float*)d_in[0];
    const int*   indices = (const int*)d_in[1];
    const float* bd      = (const float*)d_in[2];
    const float* ln_d_g  = (const float*)d_in[3];
    const float* ln_d_b  = (const float*)d_in[4];
    const float* Wd1     = (const float*)d_in[5];
    const float* bd1     = (const float*)d_in[6];
    const float* Wd2     = (const float*)d_in[7];
    const float* bd2     = (const float*)d_in[8];
    const float* ln_u_g  = (const float*)d_in[9];
    const float* ln_u_b  = (const float*)d_in[10];
    const float* Wu1     = (const float*)d_in[11];
    const float* bu1     = (const float*)d_in[12];
    const float* Wu2     = (const float*)d_in[13];
    const float* bu2     = (const float*)d_in[14];
    float* out = (float*)d_out;

    // choose largest power-of-2 group size that fits ws (h is the big buffer)
    int G = 8;
    while (G > 1) {
        size_t need = (size_t)G * NN * CC * 4 + (size_t)NN * 8 * 4 * 2
                    + (size_t)8 * NS * 4 * 2 + 2 * TT * 4
                    + (size_t)9216 * 16 + 32 * 256;
        if (need <= ws_size) break;
        G >>= 1;
    }

    char* ws = (char*)d_ws;
    size_t o = 0;
    auto alloc_b = [&](size_t bytes) { char* p = ws + o; o = (o + bytes + 255) & ~(size_t)255; return p; };
    float* h        = (float*)alloc_b((size_t)G * NN * CC * 4);
    int*   pernode  = (int*)alloc_b((size_t)NN * 8 * 4);
    int*   cursor   = (int*)alloc_b((size_t)NN * 8 * 4);
    int*   lists    = (int*)alloc_b((size_t)8 * NS * 4);
    int*   positions= (int*)alloc_b((size_t)8 * NS * 4);
    int*   cnts     = (int*)alloc_b(8 * 4);
    int*   allocg   = (int*)alloc_b(8 * 4);
    short* pW1      = (short*)alloc_b((size_t)4096 * 16);
    short* pW2      = (short*)alloc_b((size_t)2048 * 16);
    short* pW3      = (short*)alloc_b((size_t)1024 * 16);
    short* pW4      = (short*)alloc_b((size_t)2048 * 16);

    prep_weights<<<16, 256, 0, stream>>>(Wd1, pW1, 4, 4096, 256);
    prep_weights<<<8, 256, 0, stream>>>(Wd2, pW2, 8, 2048, 64);
    prep_weights<<<4, 256, 0, stream>>>(Wu1, pW3, 2, 1024, 128);
    prep_weights<<<8, 256, 0, stream>>>(Wu2, pW4, 4, 2048, 128);

    for (int g0 = 0; g0 < TT; g0 += G) {
        const float* x_g   = x + (size_t)g0 * NS * DD;
        const int*   idx_g = indices + (size_t)g0 * NS;
        float*       out_g = out + (size_t)g0 * NS * DD;

        hipMemsetAsync(pernode, 0, (size_t)NN * 8 * 4, stream);
        hipMemsetAsync(cnts, 0, 8 * 4, stream);
        hipMemsetAsync(allocg, 0, 8 * 4, stream);

        flag_kernel<<<(G * NS + 255) / 256, 256, 0, stream>>>(idx_g, pernode, G);
        compact_kernel<<<dim3((NN + 255) / 256, G), 256, 0, stream>>>(pernode, cursor,
                                                                      lists, cnts, allocg);
        fill_kernel<<<(G * NS + 255) / 256, 256, 0, stream>>>(idx_g, cursor, positions, G);
        mlp_d_kernel<<<256, 512, 0, stream>>>(x_g, bd, ln_d_g, ln_d_b, pW1, pW2,
                                              bd1, bd2, lists, cnts, pernode, cursor,
                                              positions, h, G);
        mlp_u_kernel<<<512, 512, 0, stream>>>(h, idx_g, ln_u_g, ln_u_b, pW3, pW4,
                                              bu1, bu2, out_g, G);
    }
}